// Round 3
// baseline (213.302 us; speedup 1.0000x reference)
//
#include <hip/hip_runtime.h>

// Problem constants (from reference setup_inputs)
#define BB   64          // batch
#define SS   512         // seq len
#define HH   768         // hidden dim
#define WW   256         // MAX_WORD_LEN (words per batch)
#define WE   300         // word-embedding dim
#define OUTD (HH + WE)   // 1068 output feature dim

#define WPB  8           // words per block
#define GPB  (WW / WPB)  // word-groups per batch row = 32

// R3 (= R2 resubmit; R2 bench died to infra, no verdict). Theory: R0/R1 kept
// ~1 load in flight per thread (dependent load->waitcnt->add loop), capping
// throughput at ~2 TB/s via Little's law (all pipes idle in rocprof). This
// version batches 8 independent float4 loads per round:
//  - segment bounds via LDS scatter (no dependent-load binary search),
//    broadcast to SGPRs via readfirstlane -> scalar predicates, loads issue
//    back-to-back with no exec-mask churn.
//  - rounds loop: issue up to 8 independent loads (one per live word), THEN
//    the 8 accumulates -> ~8x in-flight bytes per thread.
//  - w2v wave: load all 8 row fragments into regs, then store all 8.
__global__ __launch_bounds__(256)
void EmbeddingsModule_45311904973549_kernel(
    const float* __restrict__ hidden,     // [B, S, H]
    const float* __restrict__ w2v,        // [VOCAB, WE]
    const int*   __restrict__ token_ids,  // [B, S] sorted per row, in [0,W)
    const int*   __restrict__ word_ids,   // [B, W] in [0,VOCAB)
    float*       __restrict__ out)        // [B, W, OUTD]
{
    __shared__ int tk[SS];
    __shared__ int LB[WPB + 1];   // LB[k] = first s with tk[s] >= w0+k

    const int blk = blockIdx.x;           // 0 .. BB*GPB-1
    const int b   = blk / GPB;
    const int w0  = (blk % GPB) * WPB;
    const int tid = threadIdx.x;

    // ---- Phase 1: stage token row (512 ints, int2 per thread) + init bounds
    ((int2*)tk)[tid] = ((const int2*)(token_ids + (size_t)b * SS))[tid];
    if (tid <= WPB) LB[tid] = SS;         // default: word starts past the end
    __syncthreads();

    // ---- Phase 2: scatter segment starts for this block's 9 boundaries.
    // For position s with t=tk[s], tp=tk[s-1] (tp=-1 at s=0): every word w in
    // (tp, t] has lower_bound s. Each LB[k] is written by at most one thread.
    #pragma unroll
    for (int u = 0; u < 2; ++u) {
        const int s  = tid * 2 + u;
        const int t  = tk[s];
        const int tp = (s == 0) ? -1 : tk[s - 1];
        int klo = tp + 1 - w0; if (klo < 0)   klo = 0;
        int khi = t - w0;      if (khi > WPB) khi = WPB;
        for (int k = klo; k <= khi; ++k) LB[k] = s;
    }
    __syncthreads();

    if (tid < 192) {
        // ---- segment means: thread owns float4 column `tid` for 8 words.
        // Bounds are block-uniform -> hoist to SGPRs so per-word predicates
        // are scalar branches (loads batch up, dead words skipped free).
        const float4* hrow = (const float4*)(hidden + (size_t)b * SS * HH);

        int lo[WPB], cn[WPB];
        int maxcnt = 0;
        #pragma unroll
        for (int k = 0; k < WPB; ++k) {
            lo[k] = __builtin_amdgcn_readfirstlane(LB[k]);
            cn[k] = __builtin_amdgcn_readfirstlane(LB[k + 1]) - lo[k];
            maxcnt = (cn[k] > maxcnt) ? cn[k] : maxcnt;
        }
        if (maxcnt > SS) maxcnt = SS;     // hard bound (defensive)

        float4 acc[WPB];
        #pragma unroll
        for (int k = 0; k < WPB; ++k) acc[k] = make_float4(0.f, 0.f, 0.f, 0.f);

        for (int r = 0; r < maxcnt; ++r) {
            float4 v[WPB];
            #pragma unroll
            for (int k = 0; k < WPB; ++k) v[k] = make_float4(0.f, 0.f, 0.f, 0.f);
            // batch: up to 8 independent loads, no consumer in between
            #pragma unroll
            for (int k = 0; k < WPB; ++k)
                if (r < cn[k]) v[k] = hrow[(size_t)(lo[k] + r) * (HH / 4) + tid];
            // then consume
            #pragma unroll
            for (int k = 0; k < WPB; ++k) {
                acc[k].x += v[k].x; acc[k].y += v[k].y;
                acc[k].z += v[k].z; acc[k].w += v[k].w;
            }
        }

        #pragma unroll
        for (int k = 0; k < WPB; ++k) {
            const float inv = (cn[k] > 0) ? (1.0f / (float)cn[k]) : 0.0f;
            acc[k].x *= inv; acc[k].y *= inv; acc[k].z *= inv; acc[k].w *= inv;
            float4* orow = (float4*)(out + (size_t)(b * WW + w0 + k) * OUTD);
            orow[tid] = acc[k];           // out[b, w0+k, 0:768]
        }
    } else {
        // ---- w2v gather: 8 rows x 75 float4 with 64 threads, batched.
        const int t64 = tid - 192;
        const int* wp = word_ids + b * WW + w0;   // 32B-aligned (w0 % 8 == 0)
        const int4 wa = ((const int4*)wp)[0];
        const int4 wb = ((const int4*)wp)[1];
        const int wid[WPB] = {wa.x, wa.y, wa.z, wa.w, wb.x, wb.y, wb.z, wb.w};

        // main body: j = t64 (first 64 of 75 float4s): 8 loads then 8 stores
        float4 tmp[WPB];
        #pragma unroll
        for (int k = 0; k < WPB; ++k)
            tmp[k] = ((const float4*)(w2v + (size_t)wid[k] * WE))[t64];
        #pragma unroll
        for (int k = 0; k < WPB; ++k)
            ((float4*)(out + (size_t)(b * WW + w0 + k) * OUTD + HH))[t64] = tmp[k];

        // tail: j = 64 + t64 for t64 < 11
        if (t64 < (WE / 4 - 64)) {
            float4 t2[WPB];
            #pragma unroll
            for (int k = 0; k < WPB; ++k)
                t2[k] = ((const float4*)(w2v + (size_t)wid[k] * WE))[64 + t64];
            #pragma unroll
            for (int k = 0; k < WPB; ++k)
                ((float4*)(out + (size_t)(b * WW + w0 + k) * OUTD + HH))[64 + t64] = t2[k];
        }
    }
}

extern "C" void kernel_launch(void* const* d_in, const int* in_sizes, int n_in,
                              void* d_out, int out_size, void* d_ws, size_t ws_size,
                              hipStream_t stream) {
    const float* hidden    = (const float*)d_in[0];
    const float* w2v       = (const float*)d_in[1];
    const int*   token_ids = (const int*)d_in[2];
    const int*   word_ids  = (const int*)d_in[3];
    float*       out       = (float*)d_out;

    EmbeddingsModule_45311904973549_kernel<<<BB * GPB, 256, 0, stream>>>(
        hidden, w2v, token_ids, word_ids, out);
}